// Round 15
// baseline (1336.824 us; speedup 1.0000x reference)
//
#include <hip/hip_runtime.h>

#define NN 100000
#define EE 1600000
#define HD 128
#define GG 64
#define NB 391          // ceil(NN/256)
#define NT 8            // src tiles
#define TSZ 12500       // NN/NT exactly; 12500*256B = 3.2MB < 4MB XCD L2
#define NPW 13          // nodes per wave: ceil(100000 / 8192)
#define BNEPS 1e-5f

typedef unsigned int uint_t;
typedef unsigned short ushort_t;
typedef __attribute__((ext_vector_type(8))) short bf16x8;
typedef __attribute__((ext_vector_type(4))) float f32x4;

// fp32 -> bf16 round-to-nearest-even
static __device__ __forceinline__ ushort_t f2bf(float f){
  uint_t b = __float_as_uint(f);
  return (ushort_t)((b + 0x7FFFu + ((b >> 16) & 1u)) >> 16);
}
static __device__ __forceinline__ uint_t pack2bf(float a, float b){
  return (uint_t)f2bf(a) | ((uint_t)f2bf(b) << 16);
}
static __device__ __forceinline__ float bflo(uint_t u){ return __uint_as_float(u << 16); }
static __device__ __forceinline__ float bfhi(uint_t u){ return __uint_as_float(u & 0xFFFF0000u); }
static __device__ __forceinline__ float bf1(ushort_t u){ return __uint_as_float(((uint_t)u) << 16); }

// ---------------- 2D histogram: cnt2[dst][tile(src)] ----------------
__global__ void k_hist2(const int* __restrict__ ei, int* __restrict__ cnt2){
  int e = blockIdx.x*256 + threadIdx.x;
  if (e >= EE) return;
  int s = ei[e], d = ei[EE + e];
  atomicAdd(&cnt2[d*NT + (uint_t)s/TSZ], 1);
}

// ---------------- degree scan (deg = row-sum of cnt2) + fused dinv ----------------
__global__ void k_scanA(const int* __restrict__ cnt2, int* __restrict__ offs,
                        int* __restrict__ bsum, float* __restrict__ dinv){
  __shared__ int s[256];
  int tid = threadIdx.x;
  int n = blockIdx.x*256 + tid;
  int v = 0;
  if (n < NN){
    const int4 a = *(const int4*)&cnt2[n*NT];
    const int4 b = *(const int4*)&cnt2[n*NT + 4];
    v = a.x+a.y+a.z+a.w + b.x+b.y+b.z+b.w;
    dinv[n] = rsqrtf(1.0f + (float)v);
  }
  s[tid] = v; __syncthreads();
  for (int d = 1; d < 256; d <<= 1){
    int t = (tid >= d) ? s[tid-d] : 0;
    __syncthreads();
    s[tid] += t;
    __syncthreads();
  }
  if (n < NN) offs[n] = s[tid] - v;          // block-local exclusive
  if (tid == 255) bsum[blockIdx.x] = s[255]; // block total
}

__global__ void k_scanB(int* __restrict__ bsum){
  __shared__ int s[512];
  int tid = threadIdx.x;
  int v = (tid < NB) ? bsum[tid] : 0;
  s[tid] = v; __syncthreads();
  for (int d = 1; d < 512; d <<= 1){
    int t = (tid >= d) ? s[tid-d] : 0;
    __syncthreads();
    s[tid] += t;
    __syncthreads();
  }
  if (tid < NB) bsum[tid] = s[tid] - v;      // exclusive block bases
}

__global__ void k_scanC(int* __restrict__ offs, const int* __restrict__ bsum){
  int n = blockIdx.x*256 + threadIdx.x;
  if (n < NN) offs[n] += bsum[blockIdx.x];
  if (n == 0) offs[NN] = EE;
}

// ---------------- per-node 8-wide prefix: offs2[n*8+t] ----------------
__global__ void k_off2(const int* __restrict__ cnt2, const int* __restrict__ offs,
                       int* __restrict__ offs2){
  int n = blockIdx.x*256 + threadIdx.x;
  if (n >= NN) return;
  int base = offs[n];
  #pragma unroll
  for (int t = 0; t < NT; ++t){
    offs2[n*NT + t] = base;
    base += cnt2[n*NT + t];
  }
  if (n == 0) offs2[NN*NT] = EE;
}

// ---------------- CSR scatter (src only; weight pre-folded into hs) ----------------
__global__ void k_scatter(const int* __restrict__ ei, const int* __restrict__ offs2,
                          int* __restrict__ cursor2, int* __restrict__ csri){
  int e = blockIdx.x*256 + threadIdx.x;
  if (e >= EE) return;
  int s = ei[e], d = ei[EE + e];
  int slot = d*NT + (uint_t)s/TSZ;
  int pos = offs2[slot] + atomicAdd(&cursor2[slot], 1);
  csri[pos] = s;
}

// ---------------- W transpose+bf16 convert: Wt[c][k] = bf16(W[k][c]) ----------------
__global__ void k_wconv(const float* __restrict__ W, ushort_t* __restrict__ Wt){
  const int c = blockIdx.x, k = threadIdx.x;   // 128 x 128
  Wt[c*HD + k] = f2bf(W[k*HD + c]);
}

// ---------------- aggregation, src-tiled sweep:
//    agg[n] = (sum_{s in nbr} hs[s] + hs[n]) * dinv[n] + b,  hs = h*dinv (bf16).
//    Wave owns NPW contiguous nodes; register acc; sweep tiles t=0..7 so all
//    waves gather from the same 3.2MB hs window -> L2-hits after first touch.
//    Fused BN-stat partials. ----------------
__global__ void __launch_bounds__(256)
k_agg(const ushort_t* __restrict__ hs, const int* __restrict__ csri,
      const int* __restrict__ offs2, const float* __restrict__ dinv,
      const float* __restrict__ bias, float* __restrict__ agg,
      float* __restrict__ bns){
  const int wib  = threadIdx.x >> 6;   // wave in block (0..3)
  const int lane = threadIdx.x & 63;
  const int gw   = blockIdx.x*4 + wib; // global wave
  const int c0   = lane*2;             // 2 channels per lane
  const int n0w  = gw*NPW;
  const int jmax = (n0w < NN) ? min(NPW, NN - n0w) : 0;
  float2 acc[NPW];
  #pragma unroll
  for (int j=0;j<NPW;j++) acc[j] = make_float2(0.f,0.f);

  #pragma unroll 1
  for (int t = 0; t < NT; ++t){
    #pragma unroll
    for (int j = 0; j < NPW; ++j){
      if (j >= jmax) break;
      const int n = n0w + j;
      int e        = offs2[n*NT + t];
      const int e1 = offs2[n*NT + t + 1];
      float ax = acc[j].x, ay = acc[j].y;
      for (; e + 4 <= e1; e += 4){
        const int s0 = csri[e+0];
        const int s1 = csri[e+1];
        const int s2 = csri[e+2];
        const int s3 = csri[e+3];
        const uint_t u0 = *(const uint_t*)&hs[(size_t)s0*HD + c0];
        const uint_t u1 = *(const uint_t*)&hs[(size_t)s1*HD + c0];
        const uint_t u2 = *(const uint_t*)&hs[(size_t)s2*HD + c0];
        const uint_t u3 = *(const uint_t*)&hs[(size_t)s3*HD + c0];
        ax += bflo(u0); ay += bfhi(u0);
        ax += bflo(u1); ay += bfhi(u1);
        ax += bflo(u2); ay += bfhi(u2);
        ax += bflo(u3); ay += bfhi(u3);
      }
      for (; e < e1; ++e){
        const uint_t u = *(const uint_t*)&hs[(size_t)csri[e]*HD + c0];
        ax += bflo(u); ay += bfhi(u);
      }
      acc[j].x = ax; acc[j].y = ay;
    }
  }

  // writeout + BN stats
  const float2 b2 = *(const float2*)&bias[c0];
  float sx=0.f, sy=0.f, qx=0.f, qy=0.f;
  #pragma unroll
  for (int j = 0; j < NPW; ++j){
    if (j >= jmax) break;
    const int n = n0w + j;
    const float dn = dinv[n];
    const uint_t hv = *(const uint_t*)&hs[(size_t)n*HD + c0];
    const float ox = fmaf(acc[j].x + bflo(hv), dn, b2.x);
    const float oy = fmaf(acc[j].y + bfhi(hv), dn, b2.y);
    *(float2*)&agg[(size_t)n*HD + c0] = make_float2(ox, oy);
    sx += ox; sy += oy; qx = fmaf(ox,ox,qx); qy = fmaf(oy,oy,qy);
  }
  __shared__ float red[4][64][4];
  red[wib][lane][0]=sx; red[wib][lane][1]=sy; red[wib][lane][2]=qx; red[wib][lane][3]=qy;
  __syncthreads();
  if (wib == 0){
    float a0=0.f,a1=0.f,a2=0.f,a3=0.f;
    #pragma unroll
    for (int w=0; w<4; ++w){
      a0+=red[w][lane][0]; a1+=red[w][lane][1]; a2+=red[w][lane][2]; a3+=red[w][lane][3];
    }
    atomicAdd(&bns[c0  ],    a0);
    atomicAdd(&bns[c0+1],    a1);
    atomicAdd(&bns[HD+c0  ], a2);
    atomicAdd(&bns[HD+c0+1], a3);
  }
}

// ---------------- BN finalize: scale/shift per channel ----------------
__global__ void k_bnfin(const float* __restrict__ bns, const float* __restrict__ g,
                        const float* __restrict__ be, float* __restrict__ scale,
                        float* __restrict__ shift){
  int c = threadIdx.x;
  float m = bns[c] * (1.0f/NN);
  float v = bns[HD+c] * (1.0f/NN) - m*m;
  float sc = g[c] * rsqrtf(v + BNEPS);
  scale[c] = sc;
  shift[c] = be[c] - m*sc;
}

// ---------------- node-row GEMM via MFMA: HS(bf16, pre-scaled by dinv) = f(A)@W * dinv
// r12-verified fragment layout (absmax 2.0 pass).
// MODE 0: f=identity; 1: f=relu(bn(A)) +save HOUT(bf16); 2: +res(bf16) +save HOUT ----------------
template<int MODE>
__global__ void __launch_bounds__(256)
k_rowgemm(const float* __restrict__ A, const ushort_t* __restrict__ res,
          const ushort_t* __restrict__ Wt, const float* __restrict__ scale,
          const float* __restrict__ shift, const float* __restrict__ dinv,
          ushort_t* __restrict__ HS, ushort_t* __restrict__ HOUT){
  __shared__ ushort_t Al[64][136];     // 136 pad: 2-way LDS conflicts only
  const int tid  = threadIdx.x;
  const int wv   = tid >> 6;           // wave 0..3
  const int lane = tid & 63;
  const int n0   = blockIdx.x * 64;

  // ---- stage f(A) -> bf16 LDS (thread: node r = tid/4, channel quarter q) ----
  {
    const int r = tid >> 2;
    const int q = tid & 3;
    const int n = n0 + r;
    const int cb = q*32;
    uint_t pk[16];
    if (n < NN){
      #pragma unroll
      for (int j=0;j<8;j++){
        float4 v = *(const float4*)&A[(size_t)n*HD + cb + j*4];
        if (MODE >= 1){
          const float4 sc = *(const float4*)&scale[cb + j*4];
          const float4 sh = *(const float4*)&shift[cb + j*4];
          v.x = fmaxf(fmaf(v.x, sc.x, sh.x), 0.f);
          v.y = fmaxf(fmaf(v.y, sc.y, sh.y), 0.f);
          v.z = fmaxf(fmaf(v.z, sc.z, sh.z), 0.f);
          v.w = fmaxf(fmaf(v.w, sc.w, sh.w), 0.f);
          if (MODE == 2){
            const uint2 rv = *(const uint2*)&res[(size_t)n*HD + cb + j*4];
            v.x += bflo(rv.x); v.y += bfhi(rv.x);
            v.z += bflo(rv.y); v.w += bfhi(rv.y);
          }
          *(uint2*)&HOUT[(size_t)n*HD + cb + j*4] =
            make_uint2(pack2bf(v.x, v.y), pack2bf(v.z, v.w));
        }
        pk[2*j]   = pack2bf(v.x, v.y);
        pk[2*j+1] = pack2bf(v.z, v.w);
      }
    } else {
      #pragma unroll
      for (int i=0;i<16;i++) pk[i] = 0;
    }
    #pragma unroll
    for (int i=0;i<4;i++)
      *(uint4*)&Al[r][cb + i*8] = *(const uint4*)&pk[i*4];
  }
  __syncthreads();

  // ---- MFMA compute ----
  const int mrow = wv*16 + (lane & 15);
  const int kg8  = (lane >> 4) * 8;
  const int bcol = lane & 15;
  f32x4 acc[8];
  #pragma unroll
  for (int t=0;t<8;t++) acc[t] = (f32x4){0.f,0.f,0.f,0.f};
  #pragma unroll
  for (int ks=0; ks<4; ks++){
    const bf16x8 af = *(const bf16x8*)&Al[mrow][ks*32 + kg8];
    #pragma unroll
    for (int ct=0; ct<8; ct++){
      const bf16x8 bf = *(const bf16x8*)&Wt[(size_t)(ct*16 + bcol)*HD + ks*32 + kg8];
      acc[ct] = __builtin_amdgcn_mfma_f32_16x16x32_bf16(af, bf, acc[ct], 0, 0, 0);
    }
  }

  // ---- store D * dinv[n] as bf16 HS ----
  const int drow = wv*16 + ((lane >> 4) << 2);
  float dv[4];
  #pragma unroll
  for (int r=0;r<4;r++){
    const int n = n0 + drow + r;
    dv[r] = (n < NN) ? dinv[n] : 0.f;
  }
  #pragma unroll
  for (int ct=0; ct<8; ct++){
    #pragma unroll
    for (int r=0; r<4; r++){
      const int n = n0 + drow + r;
      if (n < NN) HS[(size_t)n*HD + ct*16 + bcol] = f2bf(acc[ct][r] * dv[r]);
    }
  }
}

// ---------------- layer-3 epilogue + segment pooling (batch is sorted) ----------------
__global__ void __launch_bounds__(128)
k_pool(const float* __restrict__ agg, const float* __restrict__ scale,
       const float* __restrict__ shift, const ushort_t* __restrict__ h2,
       const int* __restrict__ batch, float* __restrict__ pool,
       float* __restrict__ pcnt){
  const int t = threadIdx.x;
  const int n0 = blockIdx.x*128;
  const float sc = scale[t], sh = shift[t];
  float racc = 0.f;
  int cur = -1, runlen = 0;
  for (int i=0;i<128;i++){
    int n = n0 + i;
    if (n >= NN) break;
    int g = batch[n];
    float v = fmaxf(fmaf(agg[(size_t)n*HD + t], sc, sh), 0.f) + bf1(h2[(size_t)n*HD + t]);
    if (g != cur){
      if (cur >= 0){
        atomicAdd(&pool[cur*HD + t], racc);
        if (t == 0) atomicAdd(&pcnt[cur], (float)runlen);
      }
      cur = g; racc = 0.f; runlen = 0;
    }
    racc += v; runlen++;
  }
  if (cur >= 0){
    atomicAdd(&pool[cur*HD + t], racc);
    if (t == 0) atomicAdd(&pcnt[cur], (float)runlen);
  }
}

// ---------------- MLP head: relu([sum,mean] @ Wm1 + bm1) @ Wm2 + bm2 ----------------
__global__ void __launch_bounds__(128)
k_mlp(const float* __restrict__ pool, const float* __restrict__ pcnt,
      const float* __restrict__ Wm1, const float* __restrict__ bm1,
      const float* __restrict__ Wm2, const float* __restrict__ bm2,
      float* __restrict__ out){
  __shared__ float z[2*HD];
  __shared__ float red[HD];
  const int g = blockIdx.x, t = threadIdx.x;
  float s = pool[g*HD + t];
  float c = fmaxf(pcnt[g], 1.0f);
  z[t] = s; z[HD + t] = s / c;
  __syncthreads();
  float acc = bm1[t];
  for (int i=0;i<2*HD;i++) acc = fmaf(z[i], Wm1[i*HD + t], acc);
  acc = fmaxf(acc, 0.f);
  red[t] = acc * Wm2[t];
  __syncthreads();
  for (int off=64; off>0; off>>=1){
    if (t < off) red[t] += red[t+off];
    __syncthreads();
  }
  if (t == 0) out[g] = red[0] + bm2[0];
}

extern "C" void kernel_launch(void* const* d_in, const int* in_sizes, int n_in,
                              void* d_out, int out_size, void* d_ws, size_t ws_size,
                              hipStream_t stream){
  const float* x   = (const float*)d_in[0];
  const int*  ei   = (const int*)d_in[1];
  const int*  batch= (const int*)d_in[2];
  const float* W1  = (const float*)d_in[3];
  const float* b1  = (const float*)d_in[4];
  const float* W2  = (const float*)d_in[5];
  const float* b2  = (const float*)d_in[6];
  const float* W3  = (const float*)d_in[7];
  const float* b3  = (const float*)d_in[8];
  const float* g1  = (const float*)d_in[9];
  const float* be1 = (const float*)d_in[10];
  const float* g2  = (const float*)d_in[11];
  const float* be2 = (const float*)d_in[12];
  const float* g3  = (const float*)d_in[13];
  const float* be3 = (const float*)d_in[14];
  const float* Wm1 = (const float*)d_in[15];
  const float* bm1 = (const float*)d_in[16];
  const float* Wm2 = (const float*)d_in[17];
  const float* bm2 = (const float*)d_in[18];
  float* out = (float*)d_out;
  (void)in_sizes; (void)n_in; (void)out_size; (void)ws_size;

  // ---- workspace bump allocator (zeroed region first) ----
  char* p = (char*)d_ws;
  auto alloc = [&](size_t bytes)->void*{
    void* r = (void*)p;
    p += (bytes + 511) & ~(size_t)511;
    return r;
  };
  int*   cnt2    = (int*)  alloc((size_t)NN*NT*sizeof(int));   // zeroed
  int*   cursor2 = (int*)  alloc((size_t)NN*NT*sizeof(int));   // zeroed
  float* bns     = (float*)alloc(3*2*HD*sizeof(float));        // zeroed
  float* pool    = (float*)alloc(GG*HD*sizeof(float));         // zeroed
  float* pcnt    = (float*)alloc(GG*sizeof(float));            // zeroed
  size_t zbytes = (size_t)(p - (char*)d_ws);
  int*   offs   = (int*)  alloc((NN+1)*sizeof(int));
  int*   offs2  = (int*)  alloc(((size_t)NN*NT+1)*sizeof(int));
  int*   bsum   = (int*)  alloc(512*sizeof(int));
  float* dinv   = (float*)alloc(NN*sizeof(float));
  float* scale  = (float*)alloc(3*HD*sizeof(float));
  float* shift  = (float*)alloc(3*HD*sizeof(float));
  ushort_t* wt1 = (ushort_t*)alloc(HD*HD*sizeof(ushort_t)); // bf16 W^T
  ushort_t* wt2 = (ushort_t*)alloc(HD*HD*sizeof(ushort_t));
  ushort_t* wt3 = (ushort_t*)alloc(HD*HD*sizeof(ushort_t));
  int*   csri   = (int*)  alloc(((size_t)EE+8)*sizeof(int));
  ushort_t* hs  = (ushort_t*)alloc((size_t)NN*HD*sizeof(ushort_t)); // bf16 h*dinv
  float* agg    = (float*)alloc((size_t)NN*HD*sizeof(float));
  ushort_t* hres= (ushort_t*)alloc((size_t)NN*HD*sizeof(ushort_t)); // bf16 residual

  hipMemsetAsync(d_ws, 0, zbytes, stream);

  // ---- CSR build (tile-sorted) + weight conversion ----
  k_hist2  <<<(EE+255)/256, 256, 0, stream>>>(ei, cnt2);
  k_scanA  <<<NB, 256, 0, stream>>>(cnt2, offs, bsum, dinv);
  k_scanB  <<<1, 512, 0, stream>>>(bsum);
  k_scanC  <<<NB, 256, 0, stream>>>(offs, bsum);
  k_off2   <<<NB, 256, 0, stream>>>(cnt2, offs, offs2);
  k_scatter<<<(EE+255)/256, 256, 0, stream>>>(ei, offs2, cursor2, csri);
  k_wconv  <<<HD, HD, 0, stream>>>(W1, wt1);
  k_wconv  <<<HD, HD, 0, stream>>>(W2, wt2);
  k_wconv  <<<HD, HD, 0, stream>>>(W3, wt3);

  const int GB = (NN+63)/64;
  // ---- layer 1 ----
  k_rowgemm<0><<<GB, 256, 0, stream>>>(x,   nullptr, wt1, nullptr,    nullptr,    dinv, hs, nullptr);
  k_agg       <<<2048, 256, 0, stream>>>(hs, csri, offs2, dinv, b1, agg, bns);
  k_bnfin     <<<1, 128, 0, stream>>>(bns,        g1, be1, scale,      shift);
  // ---- layer 2 ----
  k_rowgemm<1><<<GB, 256, 0, stream>>>(agg, nullptr, wt2, scale,      shift,      dinv, hs, hres);
  k_agg       <<<2048, 256, 0, stream>>>(hs, csri, offs2, dinv, b2, agg, bns + 2*HD);
  k_bnfin     <<<1, 128, 0, stream>>>(bns + 2*HD, g2, be2, scale+HD,   shift+HD);
  // ---- layer 3 ----
  k_rowgemm<2><<<GB, 256, 0, stream>>>(agg, hres,    wt3, scale+HD,   shift+HD,   dinv, hs, hres);
  k_agg       <<<2048, 256, 0, stream>>>(hs, csri, offs2, dinv, b3, agg, bns + 4*HD);
  k_bnfin     <<<1, 128, 0, stream>>>(bns + 4*HD, g3, be3, scale+2*HD, shift+2*HD);

  // ---- pooling + MLP ----
  k_pool<<<(NN+127)/128, 128, 0, stream>>>(agg, scale+2*HD, shift+2*HD, hres, batch, pool, pcnt);
  k_mlp <<<GG, 128, 0, stream>>>(pool, pcnt, Wm1, bm1, Wm2, bm2, out);
}